// Round 10
// baseline (825.332 us; speedup 1.0000x reference)
//
#include <hip/hip_runtime.h>

#define HIDDEN 64
#define RSHIFT 6
#define RANGE 64      // dsts per bucket
#define SCAP 2048     // sort LDS capacity (records); mean ~1024, +32 sigma

typedef float f32x4 __attribute__((ext_vector_type(4)));
typedef short bf16x8 __attribute__((ext_vector_type(8)));
typedef unsigned int u32x4 __attribute__((ext_vector_type(4)));

union U8 {
    bf16x8 v;
    unsigned short s[8];
    unsigned int d[4];
};

__device__ __forceinline__ float lane_bcast(float v, int l) {
    return __uint_as_float(__builtin_amdgcn_readlane(__float_as_uint(v), l));
}

// bf16 round-to-nearest-even pack/unpack
__device__ __forceinline__ unsigned int f2b(float f) {
    unsigned int u = __float_as_uint(f);
    return (u + 0x7FFFu + ((u >> 16) & 1u)) >> 16;
}
__device__ __forceinline__ float b2f(unsigned int v) {
    return __uint_as_float(v << 16);
}

// =====================  x -> bf16 convert  =====================
__global__ __launch_bounds__(256) void xcvt_kernel(const float4* __restrict__ x,
                                                   ushort4* __restrict__ x16, int n4) {
    int i = blockIdx.x * blockDim.x + threadIdx.x;
    const int st = gridDim.x * blockDim.x;
    for (; i < n4; i += st) {
        const float4 v = x[i];
        ushort4 o;
        o.x = (unsigned short)f2b(v.x);
        o.y = (unsigned short)f2b(v.y);
        o.z = (unsigned short)f2b(v.z);
        o.w = (unsigned short)f2b(v.w);
        x16[i] = o;
    }
}

// =====================  bucket histogram + scan  =====================

__global__ __launch_bounds__(256) void bhist_kernel(const int* __restrict__ ei,
                                                    int* __restrict__ bcnt, int E) {
    int i = blockIdx.x * blockDim.x + threadIdx.x;
    const int st = gridDim.x * blockDim.x;
    for (; i < E; i += st) atomicAdd(&bcnt[__builtin_nontemporal_load(&ei[E + i]) >> RSHIFT], 1);
}

// Single-block multi-tile exclusive scan of bcnt[0..nb) -> boff, bcur; boff[nb]=E.
__global__ __launch_bounds__(256) void bscan_kernel(const int* __restrict__ bcnt,
                                                    int* __restrict__ boff,
                                                    int* __restrict__ bcur, int nb, int E) {
    __shared__ int s[256];
    __shared__ int carry;
    const int t = threadIdx.x;
    if (t == 0) carry = 0;
    __syncthreads();
    for (int base = 0; base < nb; base += 1024) {
        const int i0 = base + t * 4;
        int v0 = (i0 + 0 < nb) ? bcnt[i0 + 0] : 0;
        int v1 = (i0 + 1 < nb) ? bcnt[i0 + 1] : 0;
        int v2 = (i0 + 2 < nb) ? bcnt[i0 + 2] : 0;
        int v3 = (i0 + 3 < nb) ? bcnt[i0 + 3] : 0;
        const int mysum = v0 + v1 + v2 + v3;
        s[t] = mysum;
        __syncthreads();
        for (int d = 1; d < 256; d <<= 1) {
            int u = (t >= d) ? s[t - d] : 0;
            __syncthreads();
            s[t] += u;
            __syncthreads();
        }
        const int c = carry;
        const int excl = s[t] - mysum + c;
        if (i0 + 0 < nb) { boff[i0 + 0] = excl;                bcur[i0 + 0] = excl; }
        if (i0 + 1 < nb) { boff[i0 + 1] = excl + v0;           bcur[i0 + 1] = excl + v0; }
        if (i0 + 2 < nb) { boff[i0 + 2] = excl + v0 + v1;      bcur[i0 + 2] = excl + v0 + v1; }
        if (i0 + 3 < nb) { boff[i0 + 3] = excl + v0 + v1 + v2; bcur[i0 + 3] = excl + v0 + v1 + v2; }
        __syncthreads();
        if (t == 0) carry = c + s[255];
        __syncthreads();
    }
    if (t == 0) boff[nb] = E;
}

// =====================  scatter: per-BUCKET cursors, plain line-combining stores ====
// XCD dst-range grouping kept (locality); rec = {src, ea01_bf16, ea23_bf16, dstlocal}.
// Only ~nb lines are "open" at a time -> L2 write-combines -> WRITE ~= payload.
__global__ __launch_bounds__(256) void scatter_fold_kernel(const int* __restrict__ ei,
                                                           const float* __restrict__ ea,
                                                           int* __restrict__ bcur,
                                                           u32x4* __restrict__ recs, int E, int N) {
    const int grp = blockIdx.x & 7;
    const int gblk = blockIdx.x >> 3;
    const int nblk = gridDim.x >> 3;
    const int lo = (int)((long long)grp * N / 8);
    const int hi = (int)((long long)(grp + 1) * N / 8);
    int i = gblk * blockDim.x + threadIdx.x;
    const int st = nblk * blockDim.x;
    for (; i < E; i += st) {
        const int dst = __builtin_nontemporal_load(&ei[E + i]);
        if (dst >= lo && dst < hi) {
            const int src = __builtin_nontemporal_load(&ei[i]);
            const f32x4 a = __builtin_nontemporal_load((const f32x4*)&ea[(size_t)i * 4]);
            const int slot = atomicAdd(&bcur[dst >> RSHIFT], 1);
            u32x4 r;
            r.x = (unsigned int)src;
            r.y = f2b(a.x) | (f2b(a.y) << 16);
            r.z = f2b(a.z) | (f2b(a.w) << 16);
            r.w = (unsigned int)(dst & (RANGE - 1));
            recs[slot] = r;
        }
    }
}

// =====================  per-bucket LDS counting sort (in place)  =====================
// Writes per-node [off, oend). Overflow (> SCAP) leaves the segment unsorted and
// points every node at the full segment; gather's r.w filter handles both modes.
__global__ __launch_bounds__(256) void sort_kernel(u32x4* __restrict__ recs,
                                                   const int* __restrict__ boff,
                                                   int* __restrict__ off, int* __restrict__ oend,
                                                   int N) {
    __shared__ u32x4 srec[SCAP];       // 32 KB
    __shared__ int dcnt[RANGE], dbase[RANGE], dplace[RANGE];
    const int tid = threadIdx.x;
    const int b = blockIdx.x;
    const int s0 = boff[b];
    const int s1 = boff[b + 1];
    const int cnt = s1 - s0;
    const int nodebase = b << RSHIFT;

    if (cnt > SCAP) {  // degraded (astronomically rare): unsorted, full-range per node
        if (tid < RANGE) {
            const int node = nodebase + tid;
            if (node < N) {
                off[node] = s0;
                oend[node] = s1;
            }
        }
        return;
    }

    for (int i = tid; i < RANGE; i += 256) dcnt[i] = 0;
    __syncthreads();
    for (int i = tid; i < cnt; i += 256) {
        srec[i] = recs[s0 + i];
        atomicAdd(&dcnt[srec[i].w], 1);
    }
    __syncthreads();
    if (tid < 64) {  // wave 0: exclusive scan of the 64 bins
        const int mine = dcnt[tid];
        int incl = mine;
        for (int d = 1; d < 64; d <<= 1) {
            const int up = __shfl_up(incl, d);
            if (tid >= d) incl += up;
        }
        const int excl = incl - mine;
        dbase[tid] = excl;
        dplace[tid] = excl;
        const int node = nodebase + tid;
        if (node < N) {
            off[node] = s0 + excl;
            oend[node] = s0 + excl + mine;
        }
    }
    __syncthreads();
    for (int i = tid; i < cnt; i += 256) {
        const u32x4 r = srec[i];
        const int p = atomicAdd(&dplace[r.w], 1);
        recs[s0 + p] = r;
    }
}

// =====================  gather (bf16 x, sorted 16-B records)  =====================
__global__ __launch_bounds__(256) void gather16_kernel(
    const float* __restrict__ x, const unsigned short* __restrict__ x16,
    const int* __restrict__ off, const int* __restrict__ oend, const u32x4* __restrict__ recs,
    const float* __restrict__ We, const float* __restrict__ be, float* __restrict__ hout, int N) {
    const int lane = threadIdx.x & 63;
    const float w0 = We[lane];
    const float w1 = We[64 + lane];
    const float w2 = We[128 + lane];
    const float w3 = We[192 + lane];
    const float bb = be[lane];
    int wave = (blockIdx.x * blockDim.x + threadIdx.x) >> 6;
    const int nw = (gridDim.x * blockDim.x) >> 6;
    for (int n = wave; n < N; n += nw) {
        const int s0 = off[n];
        const int s1 = oend[n];
        const unsigned int dl = (unsigned int)(n & (RANGE - 1));
        float acc = x[(size_t)n * HIDDEN + lane];
        int s = s0;
        for (; s + 4 <= s1; s += 4) {
            const u32x4 r0 = __builtin_nontemporal_load(&recs[s + 0]);
            const u32x4 r1 = __builtin_nontemporal_load(&recs[s + 1]);
            const u32x4 r2 = __builtin_nontemporal_load(&recs[s + 2]);
            const u32x4 r3 = __builtin_nontemporal_load(&recs[s + 3]);
            const float x0 = b2f(x16[(size_t)r0.x * HIDDEN + lane]);
            const float x1 = b2f(x16[(size_t)r1.x * HIDDEN + lane]);
            const float x2 = b2f(x16[(size_t)r2.x * HIDDEN + lane]);
            const float x3 = b2f(x16[(size_t)r3.x * HIDDEN + lane]);
            if (r0.w == dl)
                acc += fmaxf(x0 + (bb + b2f(r0.y & 0xFFFFu) * w0 + b2f(r0.y >> 16) * w1 +
                                   b2f(r0.z & 0xFFFFu) * w2 + b2f(r0.z >> 16) * w3), 0.0f);
            if (r1.w == dl)
                acc += fmaxf(x1 + (bb + b2f(r1.y & 0xFFFFu) * w0 + b2f(r1.y >> 16) * w1 +
                                   b2f(r1.z & 0xFFFFu) * w2 + b2f(r1.z >> 16) * w3), 0.0f);
            if (r2.w == dl)
                acc += fmaxf(x2 + (bb + b2f(r2.y & 0xFFFFu) * w0 + b2f(r2.y >> 16) * w1 +
                                   b2f(r2.z & 0xFFFFu) * w2 + b2f(r2.z >> 16) * w3), 0.0f);
            if (r3.w == dl)
                acc += fmaxf(x3 + (bb + b2f(r3.y & 0xFFFFu) * w0 + b2f(r3.y >> 16) * w1 +
                                   b2f(r3.z & 0xFFFFu) * w2 + b2f(r3.z >> 16) * w3), 0.0f);
        }
        for (; s < s1; ++s) {
            const u32x4 r = __builtin_nontemporal_load(&recs[s]);
            const float xv = b2f(x16[(size_t)r.x * HIDDEN + lane]);
            if (r.w == dl)
                acc += fmaxf(xv + (bb + b2f(r.y & 0xFFFFu) * w0 + b2f(r.y >> 16) * w1 +
                                   b2f(r.z & 0xFFFFu) * w2 + b2f(r.z >> 16) * w3), 0.0f);
        }
        hout[(size_t)n * HIDDEN + lane] = acc;
    }
}

// =====================  MLP via MFMA (LDS-staged W, grid-stride)  =====================
// Same verified fragment math as round 9; W1/W2 staged coalesced into LDS once per
// block, frags built from LDS, block grid-strides over 16-node tiles.
__global__ __launch_bounds__(256) void mlp_mfma_kernel(float* __restrict__ hio,
                                                       const float* __restrict__ W1,
                                                       const float* __restrict__ b1,
                                                       const float* __restrict__ W2,
                                                       const float* __restrict__ b2, int N) {
    __shared__ unsigned short w1s[4096], w2s[4096];  // 16 KB
    __shared__ unsigned short tlds[4][16 * 72];      // 9 KB, per-wave transpose tiles
    const int tid = threadIdx.x;
    const int lane = tid & 63;
    const int wid = tid >> 6;
    const int g = lane >> 4;
    const int c = lane & 15;

    for (int i = tid; i < 4096; i += 256) {
        w1s[i] = (unsigned short)f2b(W1[i]);
        w2s[i] = (unsigned short)f2b(W2[i]);
    }
    __syncthreads();

    U8 a1[4][2], a2[4][2];
#pragma unroll
    for (int ct = 0; ct < 4; ++ct)
#pragma unroll
        for (int kk = 0; kk < 2; ++kk)
#pragma unroll
            for (int j = 0; j < 8; ++j) {
                a1[ct][kk].s[j] = w1s[(kk * 32 + g * 8 + j) * 64 + ct * 16 + c];
                a2[ct][kk].s[j] = w2s[(kk * 32 + g * 8 + j) * 64 + ct * 16 + c];
            }
    float b1c[4][4], b2c[4][4];
#pragma unroll
    for (int ct = 0; ct < 4; ++ct)
#pragma unroll
        for (int r = 0; r < 4; ++r) {
            b1c[ct][r] = b1[ct * 16 + g * 4 + r];
            b2c[ct][r] = b2[ct * 16 + g * 4 + r];
        }

    unsigned char* myb = (unsigned char*)&tlds[wid][0];
    const int ntiles = (N + 15) >> 4;

    for (int tile = blockIdx.x * 4 + wid; tile < ntiles; tile += gridDim.x * 4) {
        const int row = tile * 16 + c;
        const int rowc = min(row, N - 1);

        U8 b1f[2];
#pragma unroll
        for (int kk = 0; kk < 2; ++kk) {
            const float4* hp = (const float4*)&hio[(size_t)rowc * 64 + kk * 32 + g * 8];
            const float4 lo = hp[0];
            const float4 hi = hp[1];
            b1f[kk].d[0] = f2b(lo.x) | (f2b(lo.y) << 16);
            b1f[kk].d[1] = f2b(lo.z) | (f2b(lo.w) << 16);
            b1f[kk].d[2] = f2b(hi.x) | (f2b(hi.y) << 16);
            b1f[kk].d[3] = f2b(hi.z) | (f2b(hi.w) << 16);
        }
        f32x4 acc1[4];
#pragma unroll
        for (int ct = 0; ct < 4; ++ct) {
            acc1[ct] = (f32x4)(0.0f);
#pragma unroll
            for (int kk = 0; kk < 2; ++kk)
                acc1[ct] = __builtin_amdgcn_mfma_f32_16x16x32_bf16(a1[ct][kk].v, b1f[kk].v,
                                                                   acc1[ct], 0, 0, 0);
        }
#pragma unroll
        for (int ct = 0; ct < 4; ++ct)
#pragma unroll
            for (int rp = 0; rp < 2; ++rp) {
                const float v0 = fmaxf(acc1[ct][2 * rp + 0] + b1c[ct][2 * rp + 0], 0.0f);
                const float v1 = fmaxf(acc1[ct][2 * rp + 1] + b1c[ct][2 * rp + 1], 0.0f);
                *(unsigned int*)(myb + c * 144 + ct * 32 + g * 8 + rp * 4) =
                    f2b(v0) | (f2b(v1) << 16);
            }
        U8 b2f_[2];
#pragma unroll
        for (int kk2 = 0; kk2 < 2; ++kk2) {
            const unsigned int* q = (const unsigned int*)(myb + c * 144 + kk2 * 64 + g * 16);
            b2f_[kk2].d[0] = q[0];
            b2f_[kk2].d[1] = q[1];
            b2f_[kk2].d[2] = q[2];
            b2f_[kk2].d[3] = q[3];
        }
        f32x4 acc2[4];
#pragma unroll
        for (int ct = 0; ct < 4; ++ct) {
            acc2[ct] = (f32x4)(0.0f);
#pragma unroll
            for (int kk2 = 0; kk2 < 2; ++kk2)
                acc2[ct] = __builtin_amdgcn_mfma_f32_16x16x32_bf16(a2[ct][kk2].v, b2f_[kk2].v,
                                                                   acc2[ct], 0, 0, 0);
        }
        if (row < N) {
#pragma unroll
            for (int ct = 0; ct < 4; ++ct)
#pragma unroll
                for (int r = 0; r < 4; ++r)
                    hio[(size_t)row * 64 + ct * 16 + g * 4 + r] = acc2[ct][r] + b2c[ct][r];
        }
    }
}

// =====================  readlane MLP (fallback path only)  =====================
__global__ __launch_bounds__(256) void mlp_kernel(const float* __restrict__ hin,
                                                  const float* __restrict__ W1,
                                                  const float* __restrict__ b1,
                                                  const float* __restrict__ W2,
                                                  const float* __restrict__ b2,
                                                  float* __restrict__ out, int N) {
    const int lane = threadIdx.x & 63;
    float w1c[64], w2c[64];
#pragma unroll
    for (int k = 0; k < 64; ++k) w1c[k] = W1[k * 64 + lane];
#pragma unroll
    for (int k = 0; k < 64; ++k) w2c[k] = W2[k * 64 + lane];
    const float bb1 = b1[lane];
    const float bb2 = b2[lane];
    int wave = (blockIdx.x * blockDim.x + threadIdx.x) >> 6;
    const int nw = (gridDim.x * blockDim.x) >> 6;
    for (int n = wave; n < N; n += nw) {
        const float h = hin[(size_t)n * HIDDEN + lane];
        float t0 = bb1, t1 = 0.0f;
#pragma unroll
        for (int k = 0; k < 64; k += 2) {
            t0 = fmaf(lane_bcast(h, k), w1c[k], t0);
            t1 = fmaf(lane_bcast(h, k + 1), w1c[k + 1], t1);
        }
        const float t = fmaxf(t0 + t1, 0.0f);
        float o0 = bb2, o1 = 0.0f;
#pragma unroll
        for (int k = 0; k < 64; k += 2) {
            o0 = fmaf(lane_bcast(t, k), w2c[k], o0);
            o1 = fmaf(lane_bcast(t, k + 1), w2c[k + 1], o1);
        }
        out[(size_t)n * HIDDEN + lane] = o0 + o1;
    }
}

// =====================  fallback (ws too small): atomic path, fp32  =====================
__global__ __launch_bounds__(256) void gine_copy_kernel(const float4* __restrict__ x,
                                                        float4* __restrict__ out, int n4) {
    int i = blockIdx.x * blockDim.x + threadIdx.x;
    int stride = gridDim.x * blockDim.x;
    for (; i < n4; i += stride) out[i] = x[i];
}

__global__ __launch_bounds__(256) void gine_edge_kernel(const float* __restrict__ x,
                                                        const int* __restrict__ ei,
                                                        const float4* __restrict__ ea,
                                                        const float* __restrict__ We,
                                                        const float* __restrict__ be,
                                                        float* __restrict__ out, int E) {
    const int lane = threadIdx.x & 63;
    const float w0 = We[lane];
    const float w1 = We[64 + lane];
    const float w2 = We[128 + lane];
    const float w3 = We[192 + lane];
    const float bb = be[lane];
    int wave = (blockIdx.x * blockDim.x + threadIdx.x) >> 6;
    const int nw = (gridDim.x * blockDim.x) >> 6;
    for (int e = wave; e < E; e += nw) {
        const int src = ei[e];
        const int dst = ei[E + e];
        const float4 a = ea[e];
        float m = x[src * HIDDEN + lane] + (bb + a.x * w0 + a.y * w1 + a.z * w2 + a.w * w3);
        m = fmaxf(m, 0.0f);
        atomicAdd(out + dst * HIDDEN + lane, m);
    }
}

extern "C" void kernel_launch(void* const* d_in, const int* in_sizes, int n_in,
                              void* d_out, int out_size, void* d_ws, size_t ws_size,
                              hipStream_t stream) {
    const float* x  = (const float*)d_in[0];
    const int*   ei = (const int*)d_in[1];
    const float* ea = (const float*)d_in[2];
    const float* We = (const float*)d_in[3];
    const float* be = (const float*)d_in[4];
    const float* W1 = (const float*)d_in[5];
    const float* b1 = (const float*)d_in[6];
    const float* W2 = (const float*)d_in[7];
    const float* b2 = (const float*)d_in[8];
    float* out = (float*)d_out;

    const int N = in_sizes[0] / HIDDEN;  // 100000
    const int E = in_sizes[1] / 2;       // 1600000
    const int nb = (N + RANGE - 1) >> RSHIFT;

    // Workspace layout (h lives in d_out between gather and mlp)
    size_t p = 0;
    const size_t bcnt_ofs = p; p += ((size_t)nb * 4 + 255) & ~(size_t)255;
    const size_t boff_ofs = p; p += ((size_t)(nb + 1) * 4 + 255) & ~(size_t)255;
    const size_t bcur_ofs = p; p += ((size_t)nb * 4 + 255) & ~(size_t)255;
    const size_t off_ofs  = p; p += ((size_t)N * 4 + 255) & ~(size_t)255;
    const size_t oend_ofs = p; p += ((size_t)N * 4 + 255) & ~(size_t)255;
    const size_t rec_ofs  = p; p += (size_t)E * 16;
    const size_t x16_ofs  = p; p += ((size_t)N * HIDDEN * 2 + 255) & ~(size_t)255;
    const size_t need = p;

    if (ws_size < need) {
        gine_copy_kernel<<<2048, 256, 0, stream>>>((const float4*)x, (float4*)out,
                                                   N * (HIDDEN / 4));
        gine_edge_kernel<<<2048, 256, 0, stream>>>(x, ei, (const float4*)ea, We, be, out, E);
        mlp_kernel<<<2048, 256, 0, stream>>>(out, W1, b1, W2, b2, out, N);
        return;
    }

    char* ws = (char*)d_ws;
    int*            bcnt = (int*)(ws + bcnt_ofs);
    int*            boff = (int*)(ws + boff_ofs);
    int*            bcur = (int*)(ws + bcur_ofs);
    int*            off  = (int*)(ws + off_ofs);
    int*            oend = (int*)(ws + oend_ofs);
    u32x4*          recs = (u32x4*)(ws + rec_ofs);
    unsigned short* x16  = (unsigned short*)(ws + x16_ofs);

    xcvt_kernel<<<2048, 256, 0, stream>>>((const float4*)x, (ushort4*)x16, N * (HIDDEN / 4));
    hipMemsetAsync(bcnt, 0, (size_t)nb * 4, stream);
    bhist_kernel<<<2048, 256, 0, stream>>>(ei, bcnt, E);
    bscan_kernel<<<1, 256, 0, stream>>>(bcnt, boff, bcur, nb, E);
    scatter_fold_kernel<<<2048, 256, 0, stream>>>(ei, ea, bcur, recs, E, N);
    sort_kernel<<<nb, 256, 0, stream>>>(recs, boff, off, oend, N);
    gather16_kernel<<<2048, 256, 0, stream>>>(x, x16, off, oend, recs, We, be, out, N);
    mlp_mfma_kernel<<<640, 256, 0, stream>>>(out, W1, b1, W2, b2, N);
}

// Round 11
// 268.622 us; speedup vs baseline: 3.0725x; 3.0725x over previous
//
#include <hip/hip_runtime.h>

#define HIDDEN 64

typedef float f32x4 __attribute__((ext_vector_type(4)));
typedef short bf16x8 __attribute__((ext_vector_type(8)));
typedef unsigned int u32x4 __attribute__((ext_vector_type(4)));

union U8 {
    bf16x8 v;
    unsigned short s[8];
    unsigned int d[4];
};

__device__ __forceinline__ float lane_bcast(float v, int l) {
    return __uint_as_float(__builtin_amdgcn_readlane(__float_as_uint(v), l));
}

// bf16 round-to-nearest-even pack/unpack
__device__ __forceinline__ unsigned int f2b(float f) {
    unsigned int u = __float_as_uint(f);
    return (u + 0x7FFFu + ((u >> 16) & 1u)) >> 16;
}
__device__ __forceinline__ float b2f(unsigned int v) {
    return __uint_as_float(v << 16);
}

// =====================  x -> bf16 convert  =====================
__global__ __launch_bounds__(256) void xcvt_kernel(const float4* __restrict__ x,
                                                   ushort4* __restrict__ x16, int n4) {
    int i = blockIdx.x * blockDim.x + threadIdx.x;
    const int st = gridDim.x * blockDim.x;
    for (; i < n4; i += st) {
        const float4 v = x[i];
        ushort4 o;
        o.x = (unsigned short)f2b(v.x);
        o.y = (unsigned short)f2b(v.y);
        o.z = (unsigned short)f2b(v.z);
        o.w = (unsigned short)f2b(v.w);
        x16[i] = o;
    }
}

// =====================  CSR-build kernels (per-node, low contention)  ==============

__global__ __launch_bounds__(256) void hist_kernel(const int* __restrict__ ei, int* __restrict__ cnt,
                                                   int E) {
    int i = blockIdx.x * blockDim.x + threadIdx.x;
    int stride = gridDim.x * blockDim.x;
    for (; i < E; i += stride) atomicAdd(&cnt[__builtin_nontemporal_load(&ei[E + i])], 1);
}

__global__ __launch_bounds__(256) void scan1_kernel(int* __restrict__ cnt, int* __restrict__ partial,
                                                    int N) {
    __shared__ int s[256];
    const int t = threadIdx.x;
    const int base = blockIdx.x * 1024 + t * 4;
    int v0 = (base + 0 < N) ? cnt[base + 0] : 0;
    int v1 = (base + 1 < N) ? cnt[base + 1] : 0;
    int v2 = (base + 2 < N) ? cnt[base + 2] : 0;
    int v3 = (base + 3 < N) ? cnt[base + 3] : 0;
    const int mysum = v0 + v1 + v2 + v3;
    s[t] = mysum;
    __syncthreads();
    for (int d = 1; d < 256; d <<= 1) {
        int u = (t >= d) ? s[t - d] : 0;
        __syncthreads();
        s[t] += u;
        __syncthreads();
    }
    const int excl = s[t] - mysum;
    if (base + 0 < N) cnt[base + 0] = excl;
    if (base + 1 < N) cnt[base + 1] = excl + v0;
    if (base + 2 < N) cnt[base + 2] = excl + v0 + v1;
    if (base + 3 < N) cnt[base + 3] = excl + v0 + v1 + v2;
    if (t == 255) partial[blockIdx.x] = s[255];
}

__global__ __launch_bounds__(256) void scan2_kernel(int* __restrict__ partial, int nb) {
    __shared__ int s[256];
    const int t = threadIdx.x;
    const int mysum = (t < nb) ? partial[t] : 0;
    s[t] = mysum;
    __syncthreads();
    for (int d = 1; d < 256; d <<= 1) {
        int u = (t >= d) ? s[t - d] : 0;
        __syncthreads();
        s[t] += u;
        __syncthreads();
    }
    if (t < nb) partial[t] = s[t] - mysum;
}

__global__ __launch_bounds__(256) void scan3_kernel(int* __restrict__ off, int* __restrict__ cur,
                                                    const int* __restrict__ partial, int N, int E) {
    int i = blockIdx.x * blockDim.x + threadIdx.x;
    if (i < N) {
        const int o = off[i] + partial[i >> 10];
        off[i] = o;
        cur[i] = o;
    }
    if (i == 0) off[N] = E;
}

// =====================  scatter: NT streaming reads + PLAIN record stores  =========
// XCD dst-range grouping: group g's record region is 25.6/8 = 3.2 MB ~= its L2.
// NT loads keep streaming data OUT of L2 so open record lines survive until all
// 4 records fill -> write-back once -> WRITE ~= payload. Per-dst cursors (16
// hits avg) keep atomic contention negligible.
__global__ __launch_bounds__(256) void scatter_fold_kernel(const int* __restrict__ ei,
                                                           const float* __restrict__ ea,
                                                           int* __restrict__ cur,
                                                           u32x4* __restrict__ recs, int E, int N) {
    const int grp = blockIdx.x & 7;
    const int gblk = blockIdx.x >> 3;
    const int nblk = gridDim.x >> 3;
    const int lo = (int)((long long)grp * N / 8);
    const int hi = (int)((long long)(grp + 1) * N / 8);
    int i = gblk * blockDim.x + threadIdx.x;
    const int st = nblk * blockDim.x;
    for (; i < E; i += st) {
        const int dst = __builtin_nontemporal_load(&ei[E + i]);
        if (dst >= lo && dst < hi) {
            const int src = __builtin_nontemporal_load(&ei[i]);
            const f32x4 a = __builtin_nontemporal_load((const f32x4*)&ea[(size_t)i * 4]);
            const int slot = atomicAdd(&cur[dst], 1);
            u32x4 r;
            r.x = (unsigned int)src;
            r.y = f2b(a.x) | (f2b(a.y) << 16);
            r.z = f2b(a.z) | (f2b(a.w) << 16);
            r.w = 0u;
            recs[slot] = r;  // PLAIN store: L2 write-combines within the group's region
        }
    }
}

// =====================  gather (bf16 x, 16-B records)  =====================
__global__ __launch_bounds__(256) void gather16_kernel(
    const float* __restrict__ x, const unsigned short* __restrict__ x16,
    const int* __restrict__ off, const u32x4* __restrict__ recs,
    const float* __restrict__ We, const float* __restrict__ be, float* __restrict__ hout, int N) {
    const int lane = threadIdx.x & 63;
    const float w0 = We[lane];
    const float w1 = We[64 + lane];
    const float w2 = We[128 + lane];
    const float w3 = We[192 + lane];
    const float bb = be[lane];
    int wave = (blockIdx.x * blockDim.x + threadIdx.x) >> 6;
    const int nw = (gridDim.x * blockDim.x) >> 6;
    for (int n = wave; n < N; n += nw) {
        const int s0 = off[n];
        const int s1 = off[n + 1];
        float acc = x[(size_t)n * HIDDEN + lane];
        int s = s0;
        for (; s + 4 <= s1; s += 4) {
            const u32x4 r0 = __builtin_nontemporal_load(&recs[s + 0]);
            const u32x4 r1 = __builtin_nontemporal_load(&recs[s + 1]);
            const u32x4 r2 = __builtin_nontemporal_load(&recs[s + 2]);
            const u32x4 r3 = __builtin_nontemporal_load(&recs[s + 3]);
            const float x0 = b2f(x16[(size_t)r0.x * HIDDEN + lane]);
            const float x1 = b2f(x16[(size_t)r1.x * HIDDEN + lane]);
            const float x2 = b2f(x16[(size_t)r2.x * HIDDEN + lane]);
            const float x3 = b2f(x16[(size_t)r3.x * HIDDEN + lane]);
            acc += fmaxf(x0 + (bb + b2f(r0.y & 0xFFFFu) * w0 + b2f(r0.y >> 16) * w1 +
                               b2f(r0.z & 0xFFFFu) * w2 + b2f(r0.z >> 16) * w3), 0.0f);
            acc += fmaxf(x1 + (bb + b2f(r1.y & 0xFFFFu) * w0 + b2f(r1.y >> 16) * w1 +
                               b2f(r1.z & 0xFFFFu) * w2 + b2f(r1.z >> 16) * w3), 0.0f);
            acc += fmaxf(x2 + (bb + b2f(r2.y & 0xFFFFu) * w0 + b2f(r2.y >> 16) * w1 +
                               b2f(r2.z & 0xFFFFu) * w2 + b2f(r2.z >> 16) * w3), 0.0f);
            acc += fmaxf(x3 + (bb + b2f(r3.y & 0xFFFFu) * w0 + b2f(r3.y >> 16) * w1 +
                               b2f(r3.z & 0xFFFFu) * w2 + b2f(r3.z >> 16) * w3), 0.0f);
        }
        for (; s < s1; ++s) {
            const u32x4 r = __builtin_nontemporal_load(&recs[s]);
            const float xv = b2f(x16[(size_t)r.x * HIDDEN + lane]);
            acc += fmaxf(xv + (bb + b2f(r.y & 0xFFFFu) * w0 + b2f(r.y >> 16) * w1 +
                               b2f(r.z & 0xFFFFu) * w2 + b2f(r.z >> 16) * w3), 0.0f);
        }
        hout[(size_t)n * HIDDEN + lane] = acc;
    }
}

// =====================  MLP via MFMA (LDS-staged W, grid-stride)  =====================
// Verified fragment math (r9/r10): A-frag = W^T tile, B-frag = h rows,
// C: col=node, row=out-channel. Inter-layer transpose via padded LDS (144 B stride).
__global__ __launch_bounds__(256) void mlp_mfma_kernel(float* __restrict__ hio,
                                                       const float* __restrict__ W1,
                                                       const float* __restrict__ b1,
                                                       const float* __restrict__ W2,
                                                       const float* __restrict__ b2, int N) {
    __shared__ unsigned short w1s[4096], w2s[4096];  // 16 KB
    __shared__ unsigned short tlds[4][16 * 72];      // 9 KB, per-wave transpose tiles
    const int tid = threadIdx.x;
    const int lane = tid & 63;
    const int wid = tid >> 6;
    const int g = lane >> 4;
    const int c = lane & 15;

    for (int i = tid; i < 4096; i += 256) {
        w1s[i] = (unsigned short)f2b(W1[i]);
        w2s[i] = (unsigned short)f2b(W2[i]);
    }
    __syncthreads();

    U8 a1[4][2], a2[4][2];
#pragma unroll
    for (int ct = 0; ct < 4; ++ct)
#pragma unroll
        for (int kk = 0; kk < 2; ++kk)
#pragma unroll
            for (int j = 0; j < 8; ++j) {
                a1[ct][kk].s[j] = w1s[(kk * 32 + g * 8 + j) * 64 + ct * 16 + c];
                a2[ct][kk].s[j] = w2s[(kk * 32 + g * 8 + j) * 64 + ct * 16 + c];
            }
    float b1c[4][4], b2c[4][4];
#pragma unroll
    for (int ct = 0; ct < 4; ++ct)
#pragma unroll
        for (int r = 0; r < 4; ++r) {
            b1c[ct][r] = b1[ct * 16 + g * 4 + r];
            b2c[ct][r] = b2[ct * 16 + g * 4 + r];
        }

    unsigned char* myb = (unsigned char*)&tlds[wid][0];
    const int ntiles = (N + 15) >> 4;

    for (int tile = blockIdx.x * 4 + wid; tile < ntiles; tile += gridDim.x * 4) {
        const int row = tile * 16 + c;
        const int rowc = min(row, N - 1);

        U8 b1f[2];
#pragma unroll
        for (int kk = 0; kk < 2; ++kk) {
            const float4* hp = (const float4*)&hio[(size_t)rowc * 64 + kk * 32 + g * 8];
            const float4 lo = hp[0];
            const float4 hi = hp[1];
            b1f[kk].d[0] = f2b(lo.x) | (f2b(lo.y) << 16);
            b1f[kk].d[1] = f2b(lo.z) | (f2b(lo.w) << 16);
            b1f[kk].d[2] = f2b(hi.x) | (f2b(hi.y) << 16);
            b1f[kk].d[3] = f2b(hi.z) | (f2b(hi.w) << 16);
        }
        f32x4 acc1[4];
#pragma unroll
        for (int ct = 0; ct < 4; ++ct) {
            acc1[ct] = (f32x4)(0.0f);
#pragma unroll
            for (int kk = 0; kk < 2; ++kk)
                acc1[ct] = __builtin_amdgcn_mfma_f32_16x16x32_bf16(a1[ct][kk].v, b1f[kk].v,
                                                                   acc1[ct], 0, 0, 0);
        }
#pragma unroll
        for (int ct = 0; ct < 4; ++ct)
#pragma unroll
            for (int rp = 0; rp < 2; ++rp) {
                const float v0 = fmaxf(acc1[ct][2 * rp + 0] + b1c[ct][2 * rp + 0], 0.0f);
                const float v1 = fmaxf(acc1[ct][2 * rp + 1] + b1c[ct][2 * rp + 1], 0.0f);
                *(unsigned int*)(myb + c * 144 + ct * 32 + g * 8 + rp * 4) =
                    f2b(v0) | (f2b(v1) << 16);
            }
        U8 b2f_[2];
#pragma unroll
        for (int kk2 = 0; kk2 < 2; ++kk2) {
            const unsigned int* q = (const unsigned int*)(myb + c * 144 + kk2 * 64 + g * 16);
            b2f_[kk2].d[0] = q[0];
            b2f_[kk2].d[1] = q[1];
            b2f_[kk2].d[2] = q[2];
            b2f_[kk2].d[3] = q[3];
        }
        f32x4 acc2[4];
#pragma unroll
        for (int ct = 0; ct < 4; ++ct) {
            acc2[ct] = (f32x4)(0.0f);
#pragma unroll
            for (int kk2 = 0; kk2 < 2; ++kk2)
                acc2[ct] = __builtin_amdgcn_mfma_f32_16x16x32_bf16(a2[ct][kk2].v, b2f_[kk2].v,
                                                                   acc2[ct], 0, 0, 0);
        }
        if (row < N) {
#pragma unroll
            for (int ct = 0; ct < 4; ++ct)
#pragma unroll
                for (int r = 0; r < 4; ++r)
                    hio[(size_t)row * 64 + ct * 16 + g * 4 + r] = acc2[ct][r] + b2c[ct][r];
        }
    }
}

// =====================  readlane MLP (fallback path only)  =====================
__global__ __launch_bounds__(256) void mlp_kernel(const float* __restrict__ hin,
                                                  const float* __restrict__ W1,
                                                  const float* __restrict__ b1,
                                                  const float* __restrict__ W2,
                                                  const float* __restrict__ b2,
                                                  float* __restrict__ out, int N) {
    const int lane = threadIdx.x & 63;
    float w1c[64], w2c[64];
#pragma unroll
    for (int k = 0; k < 64; ++k) w1c[k] = W1[k * 64 + lane];
#pragma unroll
    for (int k = 0; k < 64; ++k) w2c[k] = W2[k * 64 + lane];
    const float bb1 = b1[lane];
    const float bb2 = b2[lane];
    int wave = (blockIdx.x * blockDim.x + threadIdx.x) >> 6;
    const int nw = (gridDim.x * blockDim.x) >> 6;
    for (int n = wave; n < N; n += nw) {
        const float h = hin[(size_t)n * HIDDEN + lane];
        float t0 = bb1, t1 = 0.0f;
#pragma unroll
        for (int k = 0; k < 64; k += 2) {
            t0 = fmaf(lane_bcast(h, k), w1c[k], t0);
            t1 = fmaf(lane_bcast(h, k + 1), w1c[k + 1], t1);
        }
        const float t = fmaxf(t0 + t1, 0.0f);
        float o0 = bb2, o1 = 0.0f;
#pragma unroll
        for (int k = 0; k < 64; k += 2) {
            o0 = fmaf(lane_bcast(t, k), w2c[k], o0);
            o1 = fmaf(lane_bcast(t, k + 1), w2c[k + 1], o1);
        }
        out[(size_t)n * HIDDEN + lane] = o0 + o1;
    }
}

// =====================  fallback (ws too small): atomic path, fp32  =====================
__global__ __launch_bounds__(256) void gine_copy_kernel(const float4* __restrict__ x,
                                                        float4* __restrict__ out, int n4) {
    int i = blockIdx.x * blockDim.x + threadIdx.x;
    int stride = gridDim.x * blockDim.x;
    for (; i < n4; i += stride) out[i] = x[i];
}

__global__ __launch_bounds__(256) void gine_edge_kernel(const float* __restrict__ x,
                                                        const int* __restrict__ ei,
                                                        const float4* __restrict__ ea,
                                                        const float* __restrict__ We,
                                                        const float* __restrict__ be,
                                                        float* __restrict__ out, int E) {
    const int lane = threadIdx.x & 63;
    const float w0 = We[lane];
    const float w1 = We[64 + lane];
    const float w2 = We[128 + lane];
    const float w3 = We[192 + lane];
    const float bb = be[lane];
    int wave = (blockIdx.x * blockDim.x + threadIdx.x) >> 6;
    const int nw = (gridDim.x * blockDim.x) >> 6;
    for (int e = wave; e < E; e += nw) {
        const int src = ei[e];
        const int dst = ei[E + e];
        const float4 a = ea[e];
        float m = x[src * HIDDEN + lane] + (bb + a.x * w0 + a.y * w1 + a.z * w2 + a.w * w3);
        m = fmaxf(m, 0.0f);
        atomicAdd(out + dst * HIDDEN + lane, m);
    }
}

extern "C" void kernel_launch(void* const* d_in, const int* in_sizes, int n_in,
                              void* d_out, int out_size, void* d_ws, size_t ws_size,
                              hipStream_t stream) {
    const float* x  = (const float*)d_in[0];
    const int*   ei = (const int*)d_in[1];
    const float* ea = (const float*)d_in[2];
    const float* We = (const float*)d_in[3];
    const float* be = (const float*)d_in[4];
    const float* W1 = (const float*)d_in[5];
    const float* b1 = (const float*)d_in[6];
    const float* W2 = (const float*)d_in[7];
    const float* b2 = (const float*)d_in[8];
    float* out = (float*)d_out;

    const int N = in_sizes[0] / HIDDEN;  // 100000
    const int E = in_sizes[1] / 2;       // 1600000

    // Workspace layout (h lives in d_out between gather and mlp)
    const size_t off_bytes = (size_t)(N + 1) * 4;
    size_t p = 0;
    const size_t off_ofs  = p; p += (off_bytes + 255) & ~(size_t)255;
    const size_t cur_ofs  = p; p += ((size_t)N * 4 + 255) & ~(size_t)255;
    const size_t part_ofs = p; p += 512 * 4;
    const size_t rec_ofs  = p; p += (size_t)E * 16;
    const size_t x16_ofs  = p; p += ((size_t)N * HIDDEN * 2 + 255) & ~(size_t)255;
    const size_t need = p;

    if (ws_size < need) {
        gine_copy_kernel<<<2048, 256, 0, stream>>>((const float4*)x, (float4*)out,
                                                   N * (HIDDEN / 4));
        gine_edge_kernel<<<2048, 256, 0, stream>>>(x, ei, (const float4*)ea, We, be, out, E);
        mlp_kernel<<<2048, 256, 0, stream>>>(out, W1, b1, W2, b2, out, N);
        return;
    }

    char* ws = (char*)d_ws;
    int*            off  = (int*)(ws + off_ofs);
    int*            cur  = (int*)(ws + cur_ofs);
    int*            part = (int*)(ws + part_ofs);
    u32x4*          recs = (u32x4*)(ws + rec_ofs);
    unsigned short* x16  = (unsigned short*)(ws + x16_ofs);

    const int nb_scan = (N + 1023) / 1024;  // <= 256 for N <= 262144

    xcvt_kernel<<<2048, 256, 0, stream>>>((const float4*)x, (ushort4*)x16, N * (HIDDEN / 4));
    hipMemsetAsync(off, 0, off_bytes, stream);
    hist_kernel<<<2048, 256, 0, stream>>>(ei, off, E);
    scan1_kernel<<<nb_scan, 256, 0, stream>>>(off, part, N);
    scan2_kernel<<<1, 256, 0, stream>>>(part, nb_scan);
    scan3_kernel<<<(N + 255) / 256, 256, 0, stream>>>(off, cur, part, N, E);
    scatter_fold_kernel<<<2048, 256, 0, stream>>>(ei, ea, cur, recs, E, N);
    gather16_kernel<<<2048, 256, 0, stream>>>(x, x16, off, recs, We, be, out, N);
    mlp_mfma_kernel<<<640, 256, 0, stream>>>(out, W1, b1, W2, b2, N);
}

// Round 12
// 231.791 us; speedup vs baseline: 3.5607x; 1.1589x over previous
//
#include <hip/hip_runtime.h>

#define HIDDEN 64

typedef float f32x4 __attribute__((ext_vector_type(4)));
typedef short bf16x8 __attribute__((ext_vector_type(8)));
typedef unsigned int u32x4 __attribute__((ext_vector_type(4)));

union U8 {
    bf16x8 v;
    unsigned short s[8];
    unsigned int d[4];
};

__device__ __forceinline__ float lane_bcast(float v, int l) {
    return __uint_as_float(__builtin_amdgcn_readlane(__float_as_uint(v), l));
}

// bf16 round-to-nearest-even pack; cheap unpacks of a packed pair
__device__ __forceinline__ unsigned int f2b(float f) {
    unsigned int u = __float_as_uint(f);
    return (u + 0x7FFFu + ((u >> 16) & 1u)) >> 16;
}
__device__ __forceinline__ float b2f(unsigned int v) {
    return __uint_as_float(v << 16);
}
__device__ __forceinline__ float blo(unsigned int v) {  // low bf16 of pair
    return __uint_as_float(v << 16);
}
__device__ __forceinline__ float bhi(unsigned int v) {  // high bf16 of pair
    return __uint_as_float(v & 0xFFFF0000u);
}

// =====================  prep: x->bf16 convert + dst histogram (fused)  ==============
__global__ __launch_bounds__(256) void prep_kernel(const float4* __restrict__ x,
                                                   ushort4* __restrict__ x16, int n4,
                                                   const int* __restrict__ ei,
                                                   int* __restrict__ cnt, int E) {
    const int st = gridDim.x * blockDim.x;
    for (int i = blockIdx.x * blockDim.x + threadIdx.x; i < n4; i += st) {
        const float4 v = x[i];
        ushort4 o;
        o.x = (unsigned short)f2b(v.x);
        o.y = (unsigned short)f2b(v.y);
        o.z = (unsigned short)f2b(v.z);
        o.w = (unsigned short)f2b(v.w);
        x16[i] = o;
    }
    for (int i = blockIdx.x * blockDim.x + threadIdx.x; i < E; i += st) {
        atomicAdd(&cnt[__builtin_nontemporal_load(&ei[E + i])], 1);
    }
}

// =====================  scans (per-node exact offsets)  =====================

__global__ __launch_bounds__(256) void scan1_kernel(int* __restrict__ cnt, int* __restrict__ partial,
                                                    int N) {
    __shared__ int s[256];
    const int t = threadIdx.x;
    const int base = blockIdx.x * 1024 + t * 4;
    int v0 = (base + 0 < N) ? cnt[base + 0] : 0;
    int v1 = (base + 1 < N) ? cnt[base + 1] : 0;
    int v2 = (base + 2 < N) ? cnt[base + 2] : 0;
    int v3 = (base + 3 < N) ? cnt[base + 3] : 0;
    const int mysum = v0 + v1 + v2 + v3;
    s[t] = mysum;
    __syncthreads();
    for (int d = 1; d < 256; d <<= 1) {
        int u = (t >= d) ? s[t - d] : 0;
        __syncthreads();
        s[t] += u;
        __syncthreads();
    }
    const int excl = s[t] - mysum;
    if (base + 0 < N) cnt[base + 0] = excl;
    if (base + 1 < N) cnt[base + 1] = excl + v0;
    if (base + 2 < N) cnt[base + 2] = excl + v0 + v1;
    if (base + 3 < N) cnt[base + 3] = excl + v0 + v1 + v2;
    if (t == 255) partial[blockIdx.x] = s[255];
}

__global__ __launch_bounds__(256) void scan2_kernel(int* __restrict__ partial, int nb) {
    __shared__ int s[256];
    const int t = threadIdx.x;
    const int mysum = (t < nb) ? partial[t] : 0;
    s[t] = mysum;
    __syncthreads();
    for (int d = 1; d < 256; d <<= 1) {
        int u = (t >= d) ? s[t - d] : 0;
        __syncthreads();
        s[t] += u;
        __syncthreads();
    }
    if (t < nb) partial[t] = s[t] - mysum;
}

__global__ __launch_bounds__(256) void scan3_kernel(int* __restrict__ off, int* __restrict__ cur,
                                                    const int* __restrict__ partial, int N, int E) {
    int i = blockIdx.x * blockDim.x + threadIdx.x;
    if (i < N) {
        const int o = off[i] + partial[i >> 10];
        off[i] = o;
        cur[i] = o;
    }
    if (i == 0) off[N] = E;
}

// =====================  scatter: NT streaming reads + PLAIN record stores  =========
// (r11-proven) XCD dst-range grouping keeps each group's 3.2 MB record region in
// one L2; NT loads keep streaming out of L2 -> record lines write-combine.
__global__ __launch_bounds__(256) void scatter_fold_kernel(const int* __restrict__ ei,
                                                           const float* __restrict__ ea,
                                                           int* __restrict__ cur,
                                                           u32x4* __restrict__ recs, int E, int N) {
    const int grp = blockIdx.x & 7;
    const int gblk = blockIdx.x >> 3;
    const int nblk = gridDim.x >> 3;
    const int lo = (int)((long long)grp * N / 8);
    const int hi = (int)((long long)(grp + 1) * N / 8);
    int i = gblk * blockDim.x + threadIdx.x;
    const int st = nblk * blockDim.x;
    for (; i < E; i += st) {
        const int dst = __builtin_nontemporal_load(&ei[E + i]);
        if (dst >= lo && dst < hi) {
            const int src = __builtin_nontemporal_load(&ei[i]);
            const f32x4 a = __builtin_nontemporal_load((const f32x4*)&ea[(size_t)i * 4]);
            const int slot = atomicAdd(&cur[dst], 1);
            u32x4 r;
            r.x = (unsigned int)src;
            r.y = f2b(a.x) | (f2b(a.y) << 16);
            r.z = f2b(a.z) | (f2b(a.w) << 16);
            r.w = 0u;
            recs[slot] = r;  // plain store: L2 write-combines
        }
    }
}

// =====================  gather (scalar rec loads, lean unpack)  =====================
__global__ __launch_bounds__(256) void gather16_kernel(
    const float* __restrict__ x, const unsigned short* __restrict__ x16,
    const int* __restrict__ off, const u32x4* __restrict__ recs,
    const float* __restrict__ We, const float* __restrict__ be, float* __restrict__ hout, int N) {
    const int lane = threadIdx.x & 63;
    const float w0 = We[lane];
    const float w1 = We[64 + lane];
    const float w2 = We[128 + lane];
    const float w3 = We[192 + lane];
    const float bb = be[lane];
    int wave = (blockIdx.x * blockDim.x + threadIdx.x) >> 6;
    const int nw = (gridDim.x * blockDim.x) >> 6;
    for (int n = wave; n < N; n += nw) {
        // wave-uniform segment bounds -> scalar (SGPR) record addressing
        const int s0 = __builtin_amdgcn_readfirstlane(off[n]);
        const int s1 = __builtin_amdgcn_readfirstlane(off[n + 1]);
        float acc = x[(size_t)n * HIDDEN + lane];
        int s = s0;
        for (; s + 4 <= s1; s += 4) {
            const u32x4 r0 = recs[s + 0];
            const u32x4 r1 = recs[s + 1];
            const u32x4 r2 = recs[s + 2];
            const u32x4 r3 = recs[s + 3];
            const float x0 = b2f(x16[(size_t)r0.x * HIDDEN + lane]);
            const float x1 = b2f(x16[(size_t)r1.x * HIDDEN + lane]);
            const float x2 = b2f(x16[(size_t)r2.x * HIDDEN + lane]);
            const float x3 = b2f(x16[(size_t)r3.x * HIDDEN + lane]);
            const float p0 = fmaf(bhi(r0.z), w3, fmaf(blo(r0.z), w2,
                             fmaf(bhi(r0.y), w1, fmaf(blo(r0.y), w0, bb))));
            const float p1 = fmaf(bhi(r1.z), w3, fmaf(blo(r1.z), w2,
                             fmaf(bhi(r1.y), w1, fmaf(blo(r1.y), w0, bb))));
            const float p2 = fmaf(bhi(r2.z), w3, fmaf(blo(r2.z), w2,
                             fmaf(bhi(r2.y), w1, fmaf(blo(r2.y), w0, bb))));
            const float p3 = fmaf(bhi(r3.z), w3, fmaf(blo(r3.z), w2,
                             fmaf(bhi(r3.y), w1, fmaf(blo(r3.y), w0, bb))));
            acc += fmaxf(x0 + p0, 0.0f);
            acc += fmaxf(x1 + p1, 0.0f);
            acc += fmaxf(x2 + p2, 0.0f);
            acc += fmaxf(x3 + p3, 0.0f);
        }
        for (; s < s1; ++s) {
            const u32x4 r = recs[s];
            const float xv = b2f(x16[(size_t)r.x * HIDDEN + lane]);
            const float p = fmaf(bhi(r.z), w3, fmaf(blo(r.z), w2,
                            fmaf(bhi(r.y), w1, fmaf(blo(r.y), w0, bb))));
            acc += fmaxf(xv + p, 0.0f);
        }
        hout[(size_t)n * HIDDEN + lane] = acc;
    }
}

// =====================  MLP via MFMA (LDS-staged W, grid-stride; r10-verified)  =====
__global__ __launch_bounds__(256) void mlp_mfma_kernel(float* __restrict__ hio,
                                                       const float* __restrict__ W1,
                                                       const float* __restrict__ b1,
                                                       const float* __restrict__ W2,
                                                       const float* __restrict__ b2, int N) {
    __shared__ unsigned short w1s[4096], w2s[4096];  // 16 KB
    __shared__ unsigned short tlds[4][16 * 72];      // 9 KB, per-wave transpose tiles
    const int tid = threadIdx.x;
    const int lane = tid & 63;
    const int wid = tid >> 6;
    const int g = lane >> 4;
    const int c = lane & 15;

    for (int i = tid; i < 4096; i += 256) {
        w1s[i] = (unsigned short)f2b(W1[i]);
        w2s[i] = (unsigned short)f2b(W2[i]);
    }
    __syncthreads();

    U8 a1[4][2], a2[4][2];
#pragma unroll
    for (int ct = 0; ct < 4; ++ct)
#pragma unroll
        for (int kk = 0; kk < 2; ++kk)
#pragma unroll
            for (int j = 0; j < 8; ++j) {
                a1[ct][kk].s[j] = w1s[(kk * 32 + g * 8 + j) * 64 + ct * 16 + c];
                a2[ct][kk].s[j] = w2s[(kk * 32 + g * 8 + j) * 64 + ct * 16 + c];
            }
    float b1c[4][4], b2c[4][4];
#pragma unroll
    for (int ct = 0; ct < 4; ++ct)
#pragma unroll
        for (int r = 0; r < 4; ++r) {
            b1c[ct][r] = b1[ct * 16 + g * 4 + r];
            b2c[ct][r] = b2[ct * 16 + g * 4 + r];
        }

    unsigned char* myb = (unsigned char*)&tlds[wid][0];
    const int ntiles = (N + 15) >> 4;

    for (int tile = blockIdx.x * 4 + wid; tile < ntiles; tile += gridDim.x * 4) {
        const int row = tile * 16 + c;
        const int rowc = min(row, N - 1);

        U8 b1f[2];
#pragma unroll
        for (int kk = 0; kk < 2; ++kk) {
            const float4* hp = (const float4*)&hio[(size_t)rowc * 64 + kk * 32 + g * 8];
            const float4 lo = hp[0];
            const float4 hi = hp[1];
            b1f[kk].d[0] = f2b(lo.x) | (f2b(lo.y) << 16);
            b1f[kk].d[1] = f2b(lo.z) | (f2b(lo.w) << 16);
            b1f[kk].d[2] = f2b(hi.x) | (f2b(hi.y) << 16);
            b1f[kk].d[3] = f2b(hi.z) | (f2b(hi.w) << 16);
        }
        f32x4 acc1[4];
#pragma unroll
        for (int ct = 0; ct < 4; ++ct) {
            acc1[ct] = (f32x4)(0.0f);
#pragma unroll
            for (int kk = 0; kk < 2; ++kk)
                acc1[ct] = __builtin_amdgcn_mfma_f32_16x16x32_bf16(a1[ct][kk].v, b1f[kk].v,
                                                                   acc1[ct], 0, 0, 0);
        }
#pragma unroll
        for (int ct = 0; ct < 4; ++ct)
#pragma unroll
            for (int rp = 0; rp < 2; ++rp) {
                const float v0 = fmaxf(acc1[ct][2 * rp + 0] + b1c[ct][2 * rp + 0], 0.0f);
                const float v1 = fmaxf(acc1[ct][2 * rp + 1] + b1c[ct][2 * rp + 1], 0.0f);
                *(unsigned int*)(myb + c * 144 + ct * 32 + g * 8 + rp * 4) =
                    f2b(v0) | (f2b(v1) << 16);
            }
        U8 b2f_[2];
#pragma unroll
        for (int kk2 = 0; kk2 < 2; ++kk2) {
            const unsigned int* q = (const unsigned int*)(myb + c * 144 + kk2 * 64 + g * 16);
            b2f_[kk2].d[0] = q[0];
            b2f_[kk2].d[1] = q[1];
            b2f_[kk2].d[2] = q[2];
            b2f_[kk2].d[3] = q[3];
        }
        f32x4 acc2[4];
#pragma unroll
        for (int ct = 0; ct < 4; ++ct) {
            acc2[ct] = (f32x4)(0.0f);
#pragma unroll
            for (int kk2 = 0; kk2 < 2; ++kk2)
                acc2[ct] = __builtin_amdgcn_mfma_f32_16x16x32_bf16(a2[ct][kk2].v, b2f_[kk2].v,
                                                                   acc2[ct], 0, 0, 0);
        }
        if (row < N) {
#pragma unroll
            for (int ct = 0; ct < 4; ++ct)
#pragma unroll
                for (int r = 0; r < 4; ++r)
                    hio[(size_t)row * 64 + ct * 16 + g * 4 + r] = acc2[ct][r] + b2c[ct][r];
        }
    }
}

// =====================  readlane MLP (fallback path only)  =====================
__global__ __launch_bounds__(256) void mlp_kernel(const float* __restrict__ hin,
                                                  const float* __restrict__ W1,
                                                  const float* __restrict__ b1,
                                                  const float* __restrict__ W2,
                                                  const float* __restrict__ b2,
                                                  float* __restrict__ out, int N) {
    const int lane = threadIdx.x & 63;
    float w1c[64], w2c[64];
#pragma unroll
    for (int k = 0; k < 64; ++k) w1c[k] = W1[k * 64 + lane];
#pragma unroll
    for (int k = 0; k < 64; ++k) w2c[k] = W2[k * 64 + lane];
    const float bb1 = b1[lane];
    const float bb2 = b2[lane];
    int wave = (blockIdx.x * blockDim.x + threadIdx.x) >> 6;
    const int nw = (gridDim.x * blockDim.x) >> 6;
    for (int n = wave; n < N; n += nw) {
        const float h = hin[(size_t)n * HIDDEN + lane];
        float t0 = bb1, t1 = 0.0f;
#pragma unroll
        for (int k = 0; k < 64; k += 2) {
            t0 = fmaf(lane_bcast(h, k), w1c[k], t0);
            t1 = fmaf(lane_bcast(h, k + 1), w1c[k + 1], t1);
        }
        const float t = fmaxf(t0 + t1, 0.0f);
        float o0 = bb2, o1 = 0.0f;
#pragma unroll
        for (int k = 0; k < 64; k += 2) {
            o0 = fmaf(lane_bcast(t, k), w2c[k], o0);
            o1 = fmaf(lane_bcast(t, k + 1), w2c[k + 1], o1);
        }
        out[(size_t)n * HIDDEN + lane] = o0 + o1;
    }
}

// =====================  fallback (ws too small): atomic path, fp32  =====================
__global__ __launch_bounds__(256) void gine_copy_kernel(const float4* __restrict__ x,
                                                        float4* __restrict__ out, int n4) {
    int i = blockIdx.x * blockDim.x + threadIdx.x;
    int stride = gridDim.x * blockDim.x;
    for (; i < n4; i += stride) out[i] = x[i];
}

__global__ __launch_bounds__(256) void gine_edge_kernel(const float* __restrict__ x,
                                                        const int* __restrict__ ei,
                                                        const float4* __restrict__ ea,
                                                        const float* __restrict__ We,
                                                        const float* __restrict__ be,
                                                        float* __restrict__ out, int E) {
    const int lane = threadIdx.x & 63;
    const float w0 = We[lane];
    const float w1 = We[64 + lane];
    const float w2 = We[128 + lane];
    const float w3 = We[192 + lane];
    const float bb = be[lane];
    int wave = (blockIdx.x * blockDim.x + threadIdx.x) >> 6;
    const int nw = (gridDim.x * blockDim.x) >> 6;
    for (int e = wave; e < E; e += nw) {
        const int src = ei[e];
        const int dst = ei[E + e];
        const float4 a = ea[e];
        float m = x[src * HIDDEN + lane] + (bb + a.x * w0 + a.y * w1 + a.z * w2 + a.w * w3);
        m = fmaxf(m, 0.0f);
        atomicAdd(out + dst * HIDDEN + lane, m);
    }
}

extern "C" void kernel_launch(void* const* d_in, const int* in_sizes, int n_in,
                              void* d_out, int out_size, void* d_ws, size_t ws_size,
                              hipStream_t stream) {
    const float* x  = (const float*)d_in[0];
    const int*   ei = (const int*)d_in[1];
    const float* ea = (const float*)d_in[2];
    const float* We = (const float*)d_in[3];
    const float* be = (const float*)d_in[4];
    const float* W1 = (const float*)d_in[5];
    const float* b1 = (const float*)d_in[6];
    const float* W2 = (const float*)d_in[7];
    const float* b2 = (const float*)d_in[8];
    float* out = (float*)d_out;

    const int N = in_sizes[0] / HIDDEN;  // 100000
    const int E = in_sizes[1] / 2;       // 1600000

    // Workspace layout (h lives in d_out between gather and mlp)
    const size_t off_bytes = (size_t)(N + 1) * 4;
    size_t p = 0;
    const size_t off_ofs  = p; p += (off_bytes + 255) & ~(size_t)255;
    const size_t cur_ofs  = p; p += ((size_t)N * 4 + 255) & ~(size_t)255;
    const size_t part_ofs = p; p += 512 * 4;
    const size_t rec_ofs  = p; p += (size_t)E * 16;
    const size_t x16_ofs  = p; p += ((size_t)N * HIDDEN * 2 + 255) & ~(size_t)255;
    const size_t need = p;

    if (ws_size < need) {
        gine_copy_kernel<<<2048, 256, 0, stream>>>((const float4*)x, (float4*)out,
                                                   N * (HIDDEN / 4));
        gine_edge_kernel<<<2048, 256, 0, stream>>>(x, ei, (const float4*)ea, We, be, out, E);
        mlp_kernel<<<2048, 256, 0, stream>>>(out, W1, b1, W2, b2, out, N);
        return;
    }

    char* ws = (char*)d_ws;
    int*            off  = (int*)(ws + off_ofs);
    int*            cur  = (int*)(ws + cur_ofs);
    int*            part = (int*)(ws + part_ofs);
    u32x4*          recs = (u32x4*)(ws + rec_ofs);
    unsigned short* x16  = (unsigned short*)(ws + x16_ofs);

    const int nb_scan = (N + 1023) / 1024;  // <= 256 for N <= 262144

    hipMemsetAsync(off, 0, off_bytes, stream);
    prep_kernel<<<2048, 256, 0, stream>>>((const float4*)x, (ushort4*)x16, N * (HIDDEN / 4),
                                          ei, off, E);
    scan1_kernel<<<nb_scan, 256, 0, stream>>>(off, part, N);
    scan2_kernel<<<1, 256, 0, stream>>>(part, nb_scan);
    scan3_kernel<<<(N + 255) / 256, 256, 0, stream>>>(off, cur, part, N, E);
    scatter_fold_kernel<<<2048, 256, 0, stream>>>(ei, ea, cur, recs, E, N);
    gather16_kernel<<<2048, 256, 0, stream>>>(x, x16, off, recs, We, be, out, N);
    mlp_mfma_kernel<<<640, 256, 0, stream>>>(out, W1, b1, W2, b2, N);
}